// Round 7
// baseline (256.273 us; speedup 1.0000x reference)
//
#include <hip/hip_runtime.h>
#include <math.h>

#define NN 50000
#define NE 1000000
#define EC 16            // edge chunks, chunk = e >> CSH
#define CSH 16           // chunk size 65536
#define WR 8             // counter ranges
#define RNG 6250         // counters per range (8*6250 = NN)
#define RPAD 6272        // padded dump stride (ints), block-exclusive regions
#define NCNT (EC * WR)   // 128 count blocks
#define NGB 782          // gemm L1 blocks: ceil(NN/64)

typedef __bf16 bf16x8 __attribute__((ext_vector_type(8)));
typedef float f32x4 __attribute__((ext_vector_type(4)));

__device__ inline unsigned short f2bf(float f) {          // fp32 -> bf16 RNE
    unsigned u = __float_as_uint(f);
    u += 0x7FFFu + ((u >> 16) & 1u);
    return (unsigned short)(u >> 16);
}
__device__ inline float bf2f(unsigned short s) {
    return __uint_as_float(((unsigned)s) << 16);
}
__device__ inline float bflo(unsigned r) { return __uint_as_float(r << 16); }
__device__ inline float bfhi(unsigned r) { return __uint_as_float(r & 0xffff0000u); }

// ---- prep: W1->Bt1[64][320] bf16 pad, W2->Bt2[64][64] bf16 ----
__global__ __launch_bounds__(256) void prep_init(const float* __restrict__ W1,
        const float* __restrict__ W2, unsigned short* __restrict__ Bt1,
        unsigned short* __restrict__ Bt2)
{
    int t = blockIdx.x * 256 + threadIdx.x;        // 96*256 = 24576 = 64*320+64*64
    if (t < 64 * 320) {
        int c = t / 320, k = t % 320;
        Bt1[t] = (k < 300) ? f2bf(W1[k * 64 + c]) : (unsigned short)0;
    } else {
        int i = t - 64 * 320;
        int c = i >> 6, k = i & 63;
        Bt2[i] = f2bf(W2[k * 64 + c]);
    }
}

// ---- atomic-free CSR count, STANDALONE (R5 fused variant hid which body
//      ate the time; split for attribution + full occupancy for each).
//      Block (c,w): scan chunk c (65536 edges), LDS-histogram dst range
//      [w*RNG,(w+1)*RNG); rank byte -> pos[e]; counts -> exclusive region. ----
__global__ __launch_bounds__(256) void k_count(
        const int* __restrict__ ei, int* __restrict__ cnt,
        unsigned char* __restrict__ pos)
{
    __shared__ __align__(16) int sm[RNG];          // 25000B -> 6 blocks/CU
    const int tid = threadIdx.x;
    const int bid = blockIdx.x;
    const int c = bid >> 3, w = bid & 7;
    const int lo = w * RNG;
    for (int j = tid; j < RNG; j += 256) sm[j] = 0;
    __syncthreads();
    const int base = c << CSH;
    for (int it = 0; it < (1 << CSH) / 1024; ++it) {
        int e = base + (it * 256 + tid) * 4;
        if (e < NE) {                               // NE%4==0 -> whole int4 valid
            int4 d = *(const int4*)(ei + NE + e);
            unsigned t0 = (unsigned)(d.x - lo), t1 = (unsigned)(d.y - lo);
            unsigned t2 = (unsigned)(d.z - lo), t3 = (unsigned)(d.w - lo);
            if (t0 < RNG) pos[e]     = (unsigned char)atomicAdd(&sm[t0], 1);
            if (t1 < RNG) pos[e + 1] = (unsigned char)atomicAdd(&sm[t1], 1);
            if (t2 < RNG) pos[e + 2] = (unsigned char)atomicAdd(&sm[t2], 1);
            if (t3 < RNG) pos[e + 3] = (unsigned char)atomicAdd(&sm[t3], 1);
        }
    }
    __syncthreads();
    int* dstp = cnt + (size_t)bid * RPAD;          // exclusive region
    for (int j = tid; j < RNG; j += 256) dstp[j] = sm[j];
}

// ---- L1 MFMA GEMM standalone (HEADS=8, A fp32, K=300, KT=10) ----
__global__ __launch_bounds__(256) void k_gemm(
        const float* __restrict__ A, const unsigned short* __restrict__ Bt,
        unsigned short* __restrict__ hb,
        const float* __restrict__ asrc, const float* __restrict__ adst,
        float* __restrict__ ss, float* __restrict__ sd)
{
    __shared__ unsigned short lds[5120];
    const int tid = threadIdx.x;
    const int row0 = blockIdx.x * 64;
    const int lane = tid & 63, w = tid >> 6;
    const int quad = lane >> 4, mm = lane & 15;
    const int sr = tid >> 2, q8 = (tid & 3) * 8;
    const int gsr = row0 + sr;
    const int K = 300, KT = 10, Kpad = 320, M = NN;

    f32x4 acc[4];
    #pragma unroll
    for (int i = 0; i < 4; ++i) acc[i] = (f32x4){0.f, 0.f, 0.f, 0.f};

    for (int kt = 0; kt < KT; ++kt) {
        const int k0 = kt * 32;
        int4 apack = {0, 0, 0, 0};
        if (gsr < M) {
            const float* ap = A + (size_t)gsr * K + k0 + q8;
            unsigned short* up = (unsigned short*)&apack;
            if (k0 + q8 + 7 < K) {
                float4 v0 = *(const float4*)ap;
                float4 v1 = *(const float4*)(ap + 4);
                up[0]=f2bf(v0.x); up[1]=f2bf(v0.y); up[2]=f2bf(v0.z); up[3]=f2bf(v0.w);
                up[4]=f2bf(v1.x); up[5]=f2bf(v1.y); up[6]=f2bf(v1.z); up[7]=f2bf(v1.w);
            } else {
                #pragma unroll
                for (int j = 0; j < 8; ++j)
                    up[j] = (k0 + q8 + j < K) ? f2bf(ap[j]) : (unsigned short)0;
            }
        }
        *(int4*)(lds + sr * 40 + q8) = apack;
        *(int4*)(lds + 2560 + sr * 40 + q8) =
            *(const int4*)(Bt + (size_t)sr * Kpad + k0 + q8);
        __syncthreads();
        bf16x8 af = *(const bf16x8*)(lds + (w * 16 + mm) * 40 + quad * 8);
        #pragma unroll
        for (int nt = 0; nt < 4; ++nt) {
            bf16x8 bfv = *(const bf16x8*)(lds + 2560 + (nt * 16 + mm) * 40 + quad * 8);
            acc[nt] = __builtin_amdgcn_mfma_f32_16x16x32_bf16(af, bfv, acc[nt], 0, 0, 0);
        }
        __syncthreads();
    }
    // epilogue: C (col=lane&15, row=quad*4+reg) -> LDS bf16 tile
    #pragma unroll
    for (int nt = 0; nt < 4; ++nt)
        #pragma unroll
        for (int reg = 0; reg < 4; ++reg)
            lds[w * 1152 + (quad * 4 + reg) * 72 + nt * 16 + mm] = f2bf(acc[nt][reg]);
    __syncthreads();
    const int cg = (tid & 3) * 16;
    const unsigned short* crow = lds + (sr >> 4) * 1152 + (sr & 15) * 72;
    if (gsr < M) {
        *(int4*)(hb + (size_t)gsr * 64 + cg)     = *(const int4*)(crow + cg);
        *(int4*)(hb + (size_t)gsr * 64 + cg + 8) = *(const int4*)(crow + cg + 8);
    }
    #pragma unroll
    for (int hh = 0; hh < 2; ++hh) {
        int hd = (tid & 3) + hh * 4;
        float pss = 0.f, psd = 0.f;
        #pragma unroll
        for (int c = 0; c < 8; ++c) {
            float hv = bf2f(crow[hd * 8 + c]);
            pss += hv * asrc[hd * 8 + c];
            psd += hv * adst[hd * 8 + c];
        }
        if (gsr < M) { ss[gsr * 8 + hd] = pss; sd[gsr * 8 + hd] = psd; }
    }
}

// ---- MFMA GEMM for layer 2 (A bf16, HEADS=1, K=64, KT=2), fused h+logits ----
__global__ __launch_bounds__(256) void gemm_l2(const unsigned short* __restrict__ A,
        const unsigned short* __restrict__ Bt, unsigned short* __restrict__ hb,
        const float* __restrict__ asrc, const float* __restrict__ adst,
        float* __restrict__ ss, float* __restrict__ sd)
{
    __shared__ unsigned short lds[5120];
    const int tid  = threadIdx.x;
    const int row0 = blockIdx.x * 64;
    const int lane = tid & 63, w = tid >> 6;
    const int quad = lane >> 4, mm = lane & 15;
    const int sr = tid >> 2, q8 = (tid & 3) * 8;
    const int gsr = row0 + sr;
    const int K = 64, KT = 2, Kpad = 64, M = NN;

    f32x4 acc[4];
    #pragma unroll
    for (int i = 0; i < 4; ++i) acc[i] = (f32x4){0.f, 0.f, 0.f, 0.f};

    for (int kt = 0; kt < KT; ++kt) {
        const int k0 = kt * 32;
        int4 apack = {0, 0, 0, 0};
        if (gsr < M) apack = *(const int4*)(A + (size_t)gsr * K + k0 + q8);
        *(int4*)(lds + sr * 40 + q8) = apack;
        *(int4*)(lds + 2560 + sr * 40 + q8) =
            *(const int4*)(Bt + (size_t)sr * Kpad + k0 + q8);
        __syncthreads();
        bf16x8 af = *(const bf16x8*)(lds + (w * 16 + mm) * 40 + quad * 8);
        #pragma unroll
        for (int nt = 0; nt < 4; ++nt) {
            bf16x8 bfv = *(const bf16x8*)(lds + 2560 + (nt * 16 + mm) * 40 + quad * 8);
            acc[nt] = __builtin_amdgcn_mfma_f32_16x16x32_bf16(af, bfv, acc[nt], 0, 0, 0);
        }
        __syncthreads();
    }
    #pragma unroll
    for (int nt = 0; nt < 4; ++nt)
        #pragma unroll
        for (int reg = 0; reg < 4; ++reg)
            lds[w * 1152 + (quad * 4 + reg) * 72 + nt * 16 + mm] = f2bf(acc[nt][reg]);
    __syncthreads();
    const int cg = (tid & 3) * 16;
    const unsigned short* crow = lds + (sr >> 4) * 1152 + (sr & 15) * 72;
    if (gsr < M) {
        *(int4*)(hb + (size_t)gsr * 64 + cg)     = *(const int4*)(crow + cg);
        *(int4*)(hb + (size_t)gsr * 64 + cg + 8) = *(const int4*)(crow + cg + 8);
    }
    int p = tid & 3;
    float pss = 0.f, psd = 0.f;
    #pragma unroll
    for (int c = 0; c < 16; ++c) {
        float hv = bf2f(crow[p * 16 + c]);
        pss += hv * asrc[p * 16 + c];
        psd += hv * adst[p * 16 + c];
    }
    pss += __shfl_xor(pss, 1); psd += __shfl_xor(psd, 1);
    pss += __shfl_xor(pss, 2); psd += __shfl_xor(psd, 2);
    if (p == 0 && gsr < M) { ss[gsr] = pss; sd[gsr] = psd; }
}

// ---- scan1: per-node total over 16 chunks; chunk prefixes packed as uchar16
//      (full degree < 256 -- same assumption as the uchar pos in R0-R4). ----
__global__ __launch_bounds__(1024) void scan1(const int* __restrict__ cnt,
        int* __restrict__ excl, int* __restrict__ sums,
        unsigned char* __restrict__ rpre)
{
    __shared__ int buf[1024];
    int tid = threadIdx.x;
    int i = blockIdx.x * 1024 + tid;
    int v = 0;
    if (i < NN) {
        int w = i / RNG;                    // counter range 0..7
        int j = i - w * RNG;
        int run = 0;
        unsigned pk[4] = {0, 0, 0, 0};
        #pragma unroll
        for (int c = 0; c < EC; ++c) {
            pk[c >> 2] |= ((unsigned)run & 0xffu) << ((c & 3) * 8);
            run += cnt[(size_t)(c * 8 + w) * RPAD + j];
        }
        v = run;
        *(uint4*)(rpre + (size_t)i * EC) = make_uint4(pk[0], pk[1], pk[2], pk[3]);
    }
    buf[tid] = v;
    __syncthreads();
    #pragma unroll
    for (int off = 1; off < 1024; off <<= 1) {
        int t = (tid >= off) ? buf[tid - off] : 0;
        __syncthreads();
        buf[tid] += t;
        __syncthreads();
    }
    if (i < NN) excl[i] = buf[tid] - v;
    if (tid == 1023) sums[blockIdx.x] = buf[1023];
}

// ------------- scan stage 2+3 merged: each block scans 49 sums redundantly -------------
__global__ __launch_bounds__(1024) void scan23(const int* __restrict__ excl,
        const int* __restrict__ sums, int* __restrict__ rowptr)
{
    int off = 0;
    for (int j = 0; j < (int)blockIdx.x; ++j) off += sums[j];   // uniform scalar loop
    int i = blockIdx.x * 1024 + threadIdx.x;
    if (i < NN) rowptr[i] = excl[i] + off;
    if (i == 0) rowptr[NN] = NE;
}

// ------ CSR scatter: slot = rowptr[d] + rpre[d][chunk(e)] + pos[e] ------
__global__ __launch_bounds__(256) void scatter_k(const int* __restrict__ ei,
        const int* __restrict__ rowptr, const unsigned char* __restrict__ pos,
        const unsigned char* __restrict__ rpre, unsigned short* __restrict__ col)
{
    int e = (blockIdx.x * 256 + threadIdx.x) * 4;   // NE % 4 == 0
    if (e >= NE) return;
    int c = e >> CSH;                               // chunk uniform over the int4
    int4 s = *(const int4*)(ei + e);
    int4 d = *(const int4*)(ei + NE + e);
    uchar4 p = *(const uchar4*)(pos + e);
    int r0 = rowptr[d.x] + (int)rpre[(d.x << 4) + c] + p.x;
    int r1 = rowptr[d.y] + (int)rpre[(d.y << 4) + c] + p.y;
    int r2 = rowptr[d.z] + (int)rpre[(d.z << 4) + c] + p.z;
    int r3 = rowptr[d.w] + (int)rpre[(d.w << 4) + c] + p.w;
    col[r0] = (unsigned short)s.x;
    col[r1] = (unsigned short)s.y;
    col[r2] = (unsigned short)s.z;
    col[r3] = (unsigned short)s.w;
}

#define LEAKY(s) ((s) > 0.f ? (s) : 0.2f * (s))

// ------- layer1 agg: wave/node, 16 edges in flight (4 slots x 4-deep batch) -------
__global__ __launch_bounds__(256) void agg_l1(const int* __restrict__ rowptr,
        const unsigned short* __restrict__ col, const unsigned short* __restrict__ hb,
        const float* __restrict__ ss, const float* __restrict__ sd,
        const float* __restrict__ b, unsigned short* __restrict__ out)
{
    int n = (blockIdx.x * 256 + threadIdx.x) >> 6;
    int lane = threadIdx.x & 63;
    if (n >= NN) return;
    const int es = lane >> 4;            // edge slot 0..3
    const int cg = (lane & 15) << 2;     // channel group base
    const int hd = cg >> 3;              // head
    float sdst = sd[n * 8 + hd];
    int r0 = rowptr[n], r1 = rowptr[n + 1];
    f32x4 acc = {0.f, 0.f, 0.f, 0.f};
    float dsum = 0.f;
    for (int i = r0; i < r1; i += 16) {
        int av[4]; bool vv[4];
        #pragma unroll
        for (int u = 0; u < 4; ++u) {
            int e = i + u * 4 + es;
            vv[u] = e < r1;
            av[u] = (int)col[vv[u] ? e : r0];
        }
        uint2 rr[4]; float sv[4];
        #pragma unroll
        for (int u = 0; u < 4; ++u) {
            rr[u] = *(const uint2*)(hb + av[u] * 64 + cg);
            sv[u] = ss[av[u] * 8 + hd];
        }
        #pragma unroll
        for (int u = 0; u < 4; ++u) {
            float wv = vv[u] ? __expf(LEAKY(sv[u] + sdst)) : 0.f;
            acc[0] += wv * bflo(rr[u].x);
            acc[1] += wv * bfhi(rr[u].x);
            acc[2] += wv * bflo(rr[u].y);
            acc[3] += wv * bfhi(rr[u].y);
            dsum += wv;
        }
    }
    #pragma unroll
    for (int m = 16; m <= 32; m <<= 1) {
        acc[0] += __shfl_xor(acc[0], m); acc[1] += __shfl_xor(acc[1], m);
        acc[2] += __shfl_xor(acc[2], m); acc[3] += __shfl_xor(acc[3], m);
        dsum += __shfl_xor(dsum, m);
    }
    if (es == 0) {
        float inv = 1.f / (dsum + 1e-16f);
        // ELU via __expf-1: output is bf16, so exp-1 absolute error (~1e-7) is invisible
        float v0 = acc[0] * inv + b[cg + 0]; v0 = v0 > 0.f ? v0 : __expf(v0) - 1.f;
        float v1 = acc[1] * inv + b[cg + 1]; v1 = v1 > 0.f ? v1 : __expf(v1) - 1.f;
        float v2 = acc[2] * inv + b[cg + 2]; v2 = v2 > 0.f ? v2 : __expf(v2) - 1.f;
        float v3 = acc[3] * inv + b[cg + 3]; v3 = v3 > 0.f ? v3 : __expf(v3) - 1.f;
        unsigned o01 = (unsigned)f2bf(v0) | ((unsigned)f2bf(v1) << 16);
        unsigned o23 = (unsigned)f2bf(v2) | ((unsigned)f2bf(v3) << 16);
        *(uint2*)(out + n * 64 + cg) = make_uint2(o01, o23);
    }
}

// ------- layer2 agg: wave/node, 16 edges in flight, fp32 out -------
__global__ __launch_bounds__(256) void agg_l2(const int* __restrict__ rowptr,
        const unsigned short* __restrict__ col, const unsigned short* __restrict__ hb,
        const float* __restrict__ ss, const float* __restrict__ sd,
        const float* __restrict__ b, float* __restrict__ out)
{
    int n = (blockIdx.x * 256 + threadIdx.x) >> 6;
    int lane = threadIdx.x & 63;
    if (n >= NN) return;
    const int es = lane >> 4;
    const int cg = (lane & 15) << 2;
    float sdst = sd[n];
    int r0 = rowptr[n], r1 = rowptr[n + 1];
    f32x4 acc = {0.f, 0.f, 0.f, 0.f};
    float dsum = 0.f;
    for (int i = r0; i < r1; i += 16) {
        int av[4]; bool vv[4];
        #pragma unroll
        for (int u = 0; u < 4; ++u) {
            int e = i + u * 4 + es;
            vv[u] = e < r1;
            av[u] = (int)col[vv[u] ? e : r0];
        }
        uint2 rr[4]; float sv[4];
        #pragma unroll
        for (int u = 0; u < 4; ++u) {
            rr[u] = *(const uint2*)(hb + av[u] * 64 + cg);
            sv[u] = ss[av[u]];
        }
        #pragma unroll
        for (int u = 0; u < 4; ++u) {
            float wv = vv[u] ? __expf(LEAKY(sv[u] + sdst)) : 0.f;
            acc[0] += wv * bflo(rr[u].x);
            acc[1] += wv * bfhi(rr[u].x);
            acc[2] += wv * bflo(rr[u].y);
            acc[3] += wv * bfhi(rr[u].y);
            dsum += wv;
        }
    }
    #pragma unroll
    for (int m = 16; m <= 32; m <<= 1) {
        acc[0] += __shfl_xor(acc[0], m); acc[1] += __shfl_xor(acc[1], m);
        acc[2] += __shfl_xor(acc[2], m); acc[3] += __shfl_xor(acc[3], m);
        dsum += __shfl_xor(dsum, m);
    }
    if (es == 0) {
        float inv = 1.f / (dsum + 1e-16f);
        float4 o;
        o.x = acc[0] * inv + b[cg + 0];
        o.y = acc[1] * inv + b[cg + 1];
        o.z = acc[2] * inv + b[cg + 2];
        o.w = acc[3] * inv + b[cg + 3];
        *(float4*)(out + n * 64 + cg) = o;
    }
}

extern "C" void kernel_launch(void* const* d_in, const int* in_sizes, int n_in,
                              void* d_out, int out_size, void* d_ws, size_t ws_size,
                              hipStream_t stream)
{
    const float* x      = (const float*)d_in[0];
    const int*   ei     = (const int*)d_in[1];
    const float* W1     = (const float*)d_in[2];
    const float* a_src1 = (const float*)d_in[3];
    const float* a_dst1 = (const float*)d_in[4];
    const float* b1     = (const float*)d_in[5];
    const float* W2     = (const float*)d_in[6];
    const float* a_src2 = (const float*)d_in[7];
    const float* a_dst2 = (const float*)d_in[8];
    const float* b2     = (const float*)d_in[9];
    float* out = (float*)d_out;

    // workspace (16B-aligned blocks first)
    char* wp = (char*)d_ws;
    unsigned short* hb  = (unsigned short*)wp;  wp += (size_t)NN * 64 * 2;  // h1 then h2 (bf16)
    unsigned short* P1b = (unsigned short*)wp;  wp += (size_t)NN * 64 * 2;  // h2in (bf16)
    unsigned short* Bt1 = (unsigned short*)wp;  wp += (size_t)64 * 320 * 2; // W1^T bf16 padded
    unsigned short* Bt2 = (unsigned short*)wp;  wp += (size_t)64 * 64 * 2;  // W2^T bf16
    float* ss1 = (float*)wp;  wp += (size_t)NN * 8 * 4;
    float* sd1 = (float*)wp;  wp += (size_t)NN * 8 * 4;
    int* cnt    = (int*)wp;  wp += (size_t)NCNT * RPAD * 4;  // per-(chunk,range) counts
    unsigned char* rpre = (unsigned char*)wp;  wp += (size_t)NN * EC;  // byte chunk-prefixes
    int* excl   = (int*)wp;  wp += (size_t)NN * 4;
    int* sums   = (int*)wp;  wp += 64 * 4;
    int* rowptr = (int*)wp;  wp += (size_t)(NN + 4) * 4;
    unsigned short* col = (unsigned short*)wp;  wp += (size_t)(NE + 8) * 2;
    unsigned char*  pos = (unsigned char*)wp;   wp += (size_t)NE;
    float* ss2 = ss1;                    // alias (layer1 logits dead in layer2)
    float* sd2 = ss1 + NN;

    const int NB = (NN + 1023) / 1024;   // 49

    prep_init<<<96, 256, 0, stream>>>(W1, W2, Bt1, Bt2);
    k_count<<<NCNT, 256, 0, stream>>>(ei, cnt, pos);
    k_gemm<<<NGB, 256, 0, stream>>>(x, Bt1, hb, a_src1, a_dst1, ss1, sd1);
    scan1<<<NB, 1024, 0, stream>>>(cnt, excl, sums, rpre);
    scan23<<<NB, 1024, 0, stream>>>(excl, sums, rowptr);
    scatter_k<<<(NE / 4 + 255) / 256, 256, 0, stream>>>(ei, rowptr, pos, rpre, col);

    agg_l1<<<(NN * 64 + 255) / 256, 256, 0, stream>>>(rowptr, col, hb, ss1, sd1, b1, P1b);
    gemm_l2<<<(NN + 63) / 64, 256, 0, stream>>>(P1b, Bt2, hb, a_src2, a_dst2, ss2, sd2);
    agg_l2<<<(NN * 64 + 255) / 256, 256, 0, stream>>>(rowptr, col, hb, ss2, sd2, b2, out);
}

// Round 8
// 224.838 us; speedup vs baseline: 1.1398x; 1.1398x over previous
//
#include <hip/hip_runtime.h>
#include <math.h>

#define NN 50000
#define NE 1000000
#define EC 31            // edge chunks, chunk = e >> CSH (31*32768 >= NE)
#define ECP 32           // rpre per-node stride (bytes)
#define CSH 15           // chunk size 32768
#define WR 8             // counter ranges
#define RNG 6250         // counters per range (8*6250 = NN)
#define RPAD 6272        // padded dump stride (ints), block-exclusive regions
#define NCNT (EC * WR)   // 248 count blocks
#define NGB 782          // gemm L1 blocks: ceil(NN/64)

typedef __bf16 bf16x8 __attribute__((ext_vector_type(8)));
typedef float f32x4 __attribute__((ext_vector_type(4)));

__device__ inline unsigned short f2bf(float f) {          // fp32 -> bf16 RNE
    unsigned u = __float_as_uint(f);
    u += 0x7FFFu + ((u >> 16) & 1u);
    return (unsigned short)(u >> 16);
}
__device__ inline float bf2f(unsigned short s) {
    return __uint_as_float(((unsigned)s) << 16);
}
__device__ inline float bflo(unsigned r) { return __uint_as_float(r << 16); }
__device__ inline float bfhi(unsigned r) { return __uint_as_float(r & 0xffff0000u); }

// ---- prep: W1->Bt1[64][320] bf16 pad, W2->Bt2[64][64] bf16 ----
__global__ __launch_bounds__(256) void prep_init(const float* __restrict__ W1,
        const float* __restrict__ W2, unsigned short* __restrict__ Bt1,
        unsigned short* __restrict__ Bt2)
{
    int t = blockIdx.x * 256 + threadIdx.x;        // 96*256 = 24576 = 64*320+64*64
    if (t < 64 * 320) {
        int c = t / 320, k = t % 320;
        Bt1[t] = (k < 300) ? f2bf(W1[k * 64 + c]) : (unsigned short)0;
    } else {
        int i = t - 64 * 320;
        int c = i >> 6, k = i & 63;
        Bt2[i] = f2bf(W2[k * 64 + c]);
    }
}

// ---- atomic-free CSR count. R6 showed the 128-block version ran at 4.5%
//      occupancy (0.5 blocks/CU -- half the GPU idle, 64 serial iters/block).
//      Re-shaped: 248 blocks x 1024 threads (chunk=32768, 8 iters) -> ~1
//      block/CU, 16 waves/CU. Same algorithm/LDS/semantics. ----
__global__ __launch_bounds__(1024) void k_count(
        const int* __restrict__ ei, int* __restrict__ cnt,
        unsigned char* __restrict__ pos)
{
    __shared__ __align__(16) int sm[RNG];          // 25000B
    const int tid = threadIdx.x;
    const int bid = blockIdx.x;
    const int c = bid >> 3, w = bid & 7;
    const int lo = w * RNG;
    for (int j = tid; j < RNG; j += 1024) sm[j] = 0;
    __syncthreads();
    const int base = c << CSH;
    #pragma unroll
    for (int it = 0; it < (1 << CSH) / 4096; ++it) {
        int e = base + (it * 1024 + tid) * 4;
        if (e < NE) {                               // NE%4==0 -> whole int4 valid
            int4 d = *(const int4*)(ei + NE + e);
            unsigned t0 = (unsigned)(d.x - lo), t1 = (unsigned)(d.y - lo);
            unsigned t2 = (unsigned)(d.z - lo), t3 = (unsigned)(d.w - lo);
            if (t0 < RNG) pos[e]     = (unsigned char)atomicAdd(&sm[t0], 1);
            if (t1 < RNG) pos[e + 1] = (unsigned char)atomicAdd(&sm[t1], 1);
            if (t2 < RNG) pos[e + 2] = (unsigned char)atomicAdd(&sm[t2], 1);
            if (t3 < RNG) pos[e + 3] = (unsigned char)atomicAdd(&sm[t3], 1);
        }
    }
    __syncthreads();
    int* dstp = cnt + (size_t)bid * RPAD;          // exclusive region
    for (int j = tid; j < RNG; j += 1024) dstp[j] = sm[j];
}

// ---- L1 MFMA GEMM standalone (HEADS=8, A fp32, K=300, KT=10) ----
__global__ __launch_bounds__(256) void k_gemm(
        const float* __restrict__ A, const unsigned short* __restrict__ Bt,
        unsigned short* __restrict__ hb,
        const float* __restrict__ asrc, const float* __restrict__ adst,
        float* __restrict__ ss, float* __restrict__ sd)
{
    __shared__ unsigned short lds[5120];
    const int tid = threadIdx.x;
    const int row0 = blockIdx.x * 64;
    const int lane = tid & 63, w = tid >> 6;
    const int quad = lane >> 4, mm = lane & 15;
    const int sr = tid >> 2, q8 = (tid & 3) * 8;
    const int gsr = row0 + sr;
    const int K = 300, KT = 10, Kpad = 320, M = NN;

    f32x4 acc[4];
    #pragma unroll
    for (int i = 0; i < 4; ++i) acc[i] = (f32x4){0.f, 0.f, 0.f, 0.f};

    for (int kt = 0; kt < KT; ++kt) {
        const int k0 = kt * 32;
        int4 apack = {0, 0, 0, 0};
        if (gsr < M) {
            const float* ap = A + (size_t)gsr * K + k0 + q8;
            unsigned short* up = (unsigned short*)&apack;
            if (k0 + q8 + 7 < K) {
                float4 v0 = *(const float4*)ap;
                float4 v1 = *(const float4*)(ap + 4);
                up[0]=f2bf(v0.x); up[1]=f2bf(v0.y); up[2]=f2bf(v0.z); up[3]=f2bf(v0.w);
                up[4]=f2bf(v1.x); up[5]=f2bf(v1.y); up[6]=f2bf(v1.z); up[7]=f2bf(v1.w);
            } else {
                #pragma unroll
                for (int j = 0; j < 8; ++j)
                    up[j] = (k0 + q8 + j < K) ? f2bf(ap[j]) : (unsigned short)0;
            }
        }
        *(int4*)(lds + sr * 40 + q8) = apack;
        *(int4*)(lds + 2560 + sr * 40 + q8) =
            *(const int4*)(Bt + (size_t)sr * Kpad + k0 + q8);
        __syncthreads();
        bf16x8 af = *(const bf16x8*)(lds + (w * 16 + mm) * 40 + quad * 8);
        #pragma unroll
        for (int nt = 0; nt < 4; ++nt) {
            bf16x8 bfv = *(const bf16x8*)(lds + 2560 + (nt * 16 + mm) * 40 + quad * 8);
            acc[nt] = __builtin_amdgcn_mfma_f32_16x16x32_bf16(af, bfv, acc[nt], 0, 0, 0);
        }
        __syncthreads();
    }
    // epilogue: C (col=lane&15, row=quad*4+reg) -> LDS bf16 tile
    #pragma unroll
    for (int nt = 0; nt < 4; ++nt)
        #pragma unroll
        for (int reg = 0; reg < 4; ++reg)
            lds[w * 1152 + (quad * 4 + reg) * 72 + nt * 16 + mm] = f2bf(acc[nt][reg]);
    __syncthreads();
    const int cg = (tid & 3) * 16;
    const unsigned short* crow = lds + (sr >> 4) * 1152 + (sr & 15) * 72;
    if (gsr < M) {
        *(int4*)(hb + (size_t)gsr * 64 + cg)     = *(const int4*)(crow + cg);
        *(int4*)(hb + (size_t)gsr * 64 + cg + 8) = *(const int4*)(crow + cg + 8);
    }
    #pragma unroll
    for (int hh = 0; hh < 2; ++hh) {
        int hd = (tid & 3) + hh * 4;
        float pss = 0.f, psd = 0.f;
        #pragma unroll
        for (int c = 0; c < 8; ++c) {
            float hv = bf2f(crow[hd * 8 + c]);
            pss += hv * asrc[hd * 8 + c];
            psd += hv * adst[hd * 8 + c];
        }
        if (gsr < M) { ss[gsr * 8 + hd] = pss; sd[gsr * 8 + hd] = psd; }
    }
}

// ---- MFMA GEMM for layer 2 (A bf16, HEADS=1, K=64, KT=2), fused h+logits ----
__global__ __launch_bounds__(256) void gemm_l2(const unsigned short* __restrict__ A,
        const unsigned short* __restrict__ Bt, unsigned short* __restrict__ hb,
        const float* __restrict__ asrc, const float* __restrict__ adst,
        float* __restrict__ ss, float* __restrict__ sd)
{
    __shared__ unsigned short lds[5120];
    const int tid  = threadIdx.x;
    const int row0 = blockIdx.x * 64;
    const int lane = tid & 63, w = tid >> 6;
    const int quad = lane >> 4, mm = lane & 15;
    const int sr = tid >> 2, q8 = (tid & 3) * 8;
    const int gsr = row0 + sr;
    const int K = 64, KT = 2, Kpad = 64, M = NN;

    f32x4 acc[4];
    #pragma unroll
    for (int i = 0; i < 4; ++i) acc[i] = (f32x4){0.f, 0.f, 0.f, 0.f};

    for (int kt = 0; kt < KT; ++kt) {
        const int k0 = kt * 32;
        int4 apack = {0, 0, 0, 0};
        if (gsr < M) apack = *(const int4*)(A + (size_t)gsr * K + k0 + q8);
        *(int4*)(lds + sr * 40 + q8) = apack;
        *(int4*)(lds + 2560 + sr * 40 + q8) =
            *(const int4*)(Bt + (size_t)sr * Kpad + k0 + q8);
        __syncthreads();
        bf16x8 af = *(const bf16x8*)(lds + (w * 16 + mm) * 40 + quad * 8);
        #pragma unroll
        for (int nt = 0; nt < 4; ++nt) {
            bf16x8 bfv = *(const bf16x8*)(lds + 2560 + (nt * 16 + mm) * 40 + quad * 8);
            acc[nt] = __builtin_amdgcn_mfma_f32_16x16x32_bf16(af, bfv, acc[nt], 0, 0, 0);
        }
        __syncthreads();
    }
    #pragma unroll
    for (int nt = 0; nt < 4; ++nt)
        #pragma unroll
        for (int reg = 0; reg < 4; ++reg)
            lds[w * 1152 + (quad * 4 + reg) * 72 + nt * 16 + mm] = f2bf(acc[nt][reg]);
    __syncthreads();
    const int cg = (tid & 3) * 16;
    const unsigned short* crow = lds + (sr >> 4) * 1152 + (sr & 15) * 72;
    if (gsr < M) {
        *(int4*)(hb + (size_t)gsr * 64 + cg)     = *(const int4*)(crow + cg);
        *(int4*)(hb + (size_t)gsr * 64 + cg + 8) = *(const int4*)(crow + cg + 8);
    }
    int p = tid & 3;
    float pss = 0.f, psd = 0.f;
    #pragma unroll
    for (int c = 0; c < 16; ++c) {
        float hv = bf2f(crow[p * 16 + c]);
        pss += hv * asrc[p * 16 + c];
        psd += hv * adst[p * 16 + c];
    }
    pss += __shfl_xor(pss, 1); psd += __shfl_xor(psd, 1);
    pss += __shfl_xor(pss, 2); psd += __shfl_xor(psd, 2);
    if (p == 0 && gsr < M) { ss[gsr] = pss; sd[gsr] = psd; }
}

// ---- scan1: per-node total over 31 chunks; chunk prefixes packed as bytes
//      (full degree < 256 -- same assumption as the uchar pos). ----
__global__ __launch_bounds__(1024) void scan1(const int* __restrict__ cnt,
        int* __restrict__ excl, int* __restrict__ sums,
        unsigned char* __restrict__ rpre)
{
    __shared__ int buf[1024];
    int tid = threadIdx.x;
    int i = blockIdx.x * 1024 + tid;
    int v = 0;
    if (i < NN) {
        int w = i / RNG;                    // counter range 0..7
        int j = i - w * RNG;
        int run = 0;
        unsigned pk[ECP / 4];
        #pragma unroll
        for (int q = 0; q < ECP / 4; ++q) pk[q] = 0;
        #pragma unroll
        for (int c = 0; c < EC; ++c) {
            pk[c >> 2] |= ((unsigned)run & 0xffu) << ((c & 3) * 8);
            run += cnt[(size_t)(c * 8 + w) * RPAD + j];
        }
        v = run;
        *(uint4*)(rpre + (size_t)i * ECP)      = make_uint4(pk[0], pk[1], pk[2], pk[3]);
        *(uint4*)(rpre + (size_t)i * ECP + 16) = make_uint4(pk[4], pk[5], pk[6], pk[7]);
    }
    buf[tid] = v;
    __syncthreads();
    #pragma unroll
    for (int off = 1; off < 1024; off <<= 1) {
        int t = (tid >= off) ? buf[tid - off] : 0;
        __syncthreads();
        buf[tid] += t;
        __syncthreads();
    }
    if (i < NN) excl[i] = buf[tid] - v;
    if (tid == 1023) sums[blockIdx.x] = buf[1023];
}

// ------------- scan stage 2+3 merged: each block scans 49 sums redundantly -------------
__global__ __launch_bounds__(1024) void scan23(const int* __restrict__ excl,
        const int* __restrict__ sums, int* __restrict__ rowptr)
{
    int off = 0;
    for (int j = 0; j < (int)blockIdx.x; ++j) off += sums[j];   // uniform scalar loop
    int i = blockIdx.x * 1024 + threadIdx.x;
    if (i < NN) rowptr[i] = excl[i] + off;
    if (i == 0) rowptr[NN] = NE;
}

// ------ CSR scatter: slot = rowptr[d] + rpre[d][chunk(e)] + pos[e] ------
__global__ __launch_bounds__(256) void scatter_k(const int* __restrict__ ei,
        const int* __restrict__ rowptr, const unsigned char* __restrict__ pos,
        const unsigned char* __restrict__ rpre, unsigned short* __restrict__ col)
{
    int e = (blockIdx.x * 256 + threadIdx.x) * 4;   // NE % 4 == 0
    if (e >= NE) return;
    int c = e >> CSH;                               // chunk uniform over the int4
    int4 s = *(const int4*)(ei + e);
    int4 d = *(const int4*)(ei + NE + e);
    uchar4 p = *(const uchar4*)(pos + e);
    int r0 = rowptr[d.x] + (int)rpre[(d.x << 5) + c] + p.x;
    int r1 = rowptr[d.y] + (int)rpre[(d.y << 5) + c] + p.y;
    int r2 = rowptr[d.z] + (int)rpre[(d.z << 5) + c] + p.z;
    int r3 = rowptr[d.w] + (int)rpre[(d.w << 5) + c] + p.w;
    col[r0] = (unsigned short)s.x;
    col[r1] = (unsigned short)s.y;
    col[r2] = (unsigned short)s.z;
    col[r3] = (unsigned short)s.w;
}

#define LEAKY(s) ((s) > 0.f ? (s) : 0.2f * (s))

// ------- layer1 agg: wave/node, 16 edges in flight (4 slots x 4-deep batch) -------
__global__ __launch_bounds__(256) void agg_l1(const int* __restrict__ rowptr,
        const unsigned short* __restrict__ col, const unsigned short* __restrict__ hb,
        const float* __restrict__ ss, const float* __restrict__ sd,
        const float* __restrict__ b, unsigned short* __restrict__ out)
{
    int n = (blockIdx.x * 256 + threadIdx.x) >> 6;
    int lane = threadIdx.x & 63;
    if (n >= NN) return;
    const int es = lane >> 4;            // edge slot 0..3
    const int cg = (lane & 15) << 2;     // channel group base
    const int hd = cg >> 3;              // head
    float sdst = sd[n * 8 + hd];
    int r0 = rowptr[n], r1 = rowptr[n + 1];
    f32x4 acc = {0.f, 0.f, 0.f, 0.f};
    float dsum = 0.f;
    for (int i = r0; i < r1; i += 16) {
        int av[4]; bool vv[4];
        #pragma unroll
        for (int u = 0; u < 4; ++u) {
            int e = i + u * 4 + es;
            vv[u] = e < r1;
            av[u] = (int)col[vv[u] ? e : r0];
        }
        uint2 rr[4]; float sv[4];
        #pragma unroll
        for (int u = 0; u < 4; ++u) {
            rr[u] = *(const uint2*)(hb + av[u] * 64 + cg);
            sv[u] = ss[av[u] * 8 + hd];
        }
        #pragma unroll
        for (int u = 0; u < 4; ++u) {
            float wv = vv[u] ? __expf(LEAKY(sv[u] + sdst)) : 0.f;
            acc[0] += wv * bflo(rr[u].x);
            acc[1] += wv * bfhi(rr[u].x);
            acc[2] += wv * bflo(rr[u].y);
            acc[3] += wv * bfhi(rr[u].y);
            dsum += wv;
        }
    }
    #pragma unroll
    for (int m = 16; m <= 32; m <<= 1) {
        acc[0] += __shfl_xor(acc[0], m); acc[1] += __shfl_xor(acc[1], m);
        acc[2] += __shfl_xor(acc[2], m); acc[3] += __shfl_xor(acc[3], m);
        dsum += __shfl_xor(dsum, m);
    }
    if (es == 0) {
        float inv = 1.f / (dsum + 1e-16f);
        // ELU via __expf-1: output is bf16, so exp-1 absolute error (~1e-7) is invisible
        float v0 = acc[0] * inv + b[cg + 0]; v0 = v0 > 0.f ? v0 : __expf(v0) - 1.f;
        float v1 = acc[1] * inv + b[cg + 1]; v1 = v1 > 0.f ? v1 : __expf(v1) - 1.f;
        float v2 = acc[2] * inv + b[cg + 2]; v2 = v2 > 0.f ? v2 : __expf(v2) - 1.f;
        float v3 = acc[3] * inv + b[cg + 3]; v3 = v3 > 0.f ? v3 : __expf(v3) - 1.f;
        unsigned o01 = (unsigned)f2bf(v0) | ((unsigned)f2bf(v1) << 16);
        unsigned o23 = (unsigned)f2bf(v2) | ((unsigned)f2bf(v3) << 16);
        *(uint2*)(out + n * 64 + cg) = make_uint2(o01, o23);
    }
}

// ------- layer2 agg: wave/node, 16 edges in flight, fp32 out -------
__global__ __launch_bounds__(256) void agg_l2(const int* __restrict__ rowptr,
        const unsigned short* __restrict__ col, const unsigned short* __restrict__ hb,
        const float* __restrict__ ss, const float* __restrict__ sd,
        const float* __restrict__ b, float* __restrict__ out)
{
    int n = (blockIdx.x * 256 + threadIdx.x) >> 6;
    int lane = threadIdx.x & 63;
    if (n >= NN) return;
    const int es = lane >> 4;
    const int cg = (lane & 15) << 2;
    float sdst = sd[n];
    int r0 = rowptr[n], r1 = rowptr[n + 1];
    f32x4 acc = {0.f, 0.f, 0.f, 0.f};
    float dsum = 0.f;
    for (int i = r0; i < r1; i += 16) {
        int av[4]; bool vv[4];
        #pragma unroll
        for (int u = 0; u < 4; ++u) {
            int e = i + u * 4 + es;
            vv[u] = e < r1;
            av[u] = (int)col[vv[u] ? e : r0];
        }
        uint2 rr[4]; float sv[4];
        #pragma unroll
        for (int u = 0; u < 4; ++u) {
            rr[u] = *(const uint2*)(hb + av[u] * 64 + cg);
            sv[u] = ss[av[u]];
        }
        #pragma unroll
        for (int u = 0; u < 4; ++u) {
            float wv = vv[u] ? __expf(LEAKY(sv[u] + sdst)) : 0.f;
            acc[0] += wv * bflo(rr[u].x);
            acc[1] += wv * bfhi(rr[u].x);
            acc[2] += wv * bflo(rr[u].y);
            acc[3] += wv * bfhi(rr[u].y);
            dsum += wv;
        }
    }
    #pragma unroll
    for (int m = 16; m <= 32; m <<= 1) {
        acc[0] += __shfl_xor(acc[0], m); acc[1] += __shfl_xor(acc[1], m);
        acc[2] += __shfl_xor(acc[2], m); acc[3] += __shfl_xor(acc[3], m);
        dsum += __shfl_xor(dsum, m);
    }
    if (es == 0) {
        float inv = 1.f / (dsum + 1e-16f);
        float4 o;
        o.x = acc[0] * inv + b[cg + 0];
        o.y = acc[1] * inv + b[cg + 1];
        o.z = acc[2] * inv + b[cg + 2];
        o.w = acc[3] * inv + b[cg + 3];
        *(float4*)(out + n * 64 + cg) = o;
    }
}

extern "C" void kernel_launch(void* const* d_in, const int* in_sizes, int n_in,
                              void* d_out, int out_size, void* d_ws, size_t ws_size,
                              hipStream_t stream)
{
    const float* x      = (const float*)d_in[0];
    const int*   ei     = (const int*)d_in[1];
    const float* W1     = (const float*)d_in[2];
    const float* a_src1 = (const float*)d_in[3];
    const float* a_dst1 = (const float*)d_in[4];
    const float* b1     = (const float*)d_in[5];
    const float* W2     = (const float*)d_in[6];
    const float* a_src2 = (const float*)d_in[7];
    const float* a_dst2 = (const float*)d_in[8];
    const float* b2     = (const float*)d_in[9];
    float* out = (float*)d_out;

    // workspace (16B-aligned blocks first)
    char* wp = (char*)d_ws;
    unsigned short* hb  = (unsigned short*)wp;  wp += (size_t)NN * 64 * 2;  // h1 then h2 (bf16)
    unsigned short* P1b = (unsigned short*)wp;  wp += (size_t)NN * 64 * 2;  // h2in (bf16)
    unsigned short* Bt1 = (unsigned short*)wp;  wp += (size_t)64 * 320 * 2; // W1^T bf16 padded
    unsigned short* Bt2 = (unsigned short*)wp;  wp += (size_t)64 * 64 * 2;  // W2^T bf16
    float* ss1 = (float*)wp;  wp += (size_t)NN * 8 * 4;
    float* sd1 = (float*)wp;  wp += (size_t)NN * 8 * 4;
    int* cnt    = (int*)wp;  wp += (size_t)NCNT * RPAD * 4;  // per-(chunk,range) counts
    unsigned char* rpre = (unsigned char*)wp;  wp += (size_t)NN * ECP;  // byte chunk-prefixes
    int* excl   = (int*)wp;  wp += (size_t)NN * 4;
    int* sums   = (int*)wp;  wp += 64 * 4;
    int* rowptr = (int*)wp;  wp += (size_t)(NN + 4) * 4;
    unsigned short* col = (unsigned short*)wp;  wp += (size_t)(NE + 8) * 2;
    unsigned char*  pos = (unsigned char*)wp;   wp += (size_t)NE;
    float* ss2 = ss1;                    // alias (layer1 logits dead in layer2)
    float* sd2 = ss1 + NN;

    const int NB = (NN + 1023) / 1024;   // 49

    prep_init<<<96, 256, 0, stream>>>(W1, W2, Bt1, Bt2);
    k_count<<<NCNT, 1024, 0, stream>>>(ei, cnt, pos);
    k_gemm<<<NGB, 256, 0, stream>>>(x, Bt1, hb, a_src1, a_dst1, ss1, sd1);
    scan1<<<NB, 1024, 0, stream>>>(cnt, excl, sums, rpre);
    scan23<<<NB, 1024, 0, stream>>>(excl, sums, rowptr);
    scatter_k<<<(NE / 4 + 255) / 256, 256, 0, stream>>>(ei, rowptr, pos, rpre, col);

    agg_l1<<<(NN * 64 + 255) / 256, 256, 0, stream>>>(rowptr, col, hb, ss1, sd1, b1, P1b);
    gemm_l2<<<(NN + 63) / 64, 256, 0, stream>>>(P1b, Bt2, hb, a_src2, a_dst2, ss2, sd2);
    agg_l2<<<(NN * 64 + 255) / 256, 256, 0, stream>>>(rowptr, col, hb, ss2, sd2, b2, out);
}

// Round 9
// 223.437 us; speedup vs baseline: 1.1470x; 1.0063x over previous
//
#include <hip/hip_runtime.h>
#include <math.h>

#define NN 50000
#define NE 1000000
#define EC 31            // edge chunks, chunk = e >> CSH (31*32768 >= NE)
#define ECP 32           // rpre per-node stride (bytes)
#define CSH 15           // chunk size 32768
#define WR 8             // counter ranges
#define RNG 6250         // counters per range (8*6250 = NN)
#define RPAD 6272        // padded dump stride (ints), block-exclusive regions
#define NCNT (EC * WR)   // 248 count blocks
#define NPB 24           // prep blocks (24*1024 = 24576 = 64*320+64*64)
#define NGB 782          // gemm L1 blocks: ceil(NN/64)
#define NSB 196          // scan1 blocks (196*256 >= NN)

typedef __bf16 bf16x8 __attribute__((ext_vector_type(8)));
typedef float f32x4 __attribute__((ext_vector_type(4)));

__device__ inline unsigned short f2bf(float f) {          // fp32 -> bf16 RNE
    unsigned u = __float_as_uint(f);
    u += 0x7FFFu + ((u >> 16) & 1u);
    return (unsigned short)(u >> 16);
}
__device__ inline float bf2f(unsigned short s) {
    return __uint_as_float(((unsigned)s) << 16);
}
__device__ inline float bflo(unsigned r) { return __uint_as_float(r << 16); }
__device__ inline float bfhi(unsigned r) { return __uint_as_float(r & 0xffff0000u); }

// ---- FUSED: CSR count (blocks [0,NCNT)) + weight prep (tail blocks).
//      Count: R7's 248x1024 LDS-histogram shape (atomic-free, ~50% occ). ----
__global__ __launch_bounds__(1024) void k_count_prep(
        const int* __restrict__ ei, int* __restrict__ cnt,
        unsigned char* __restrict__ pos,
        const float* __restrict__ W1, const float* __restrict__ W2,
        unsigned short* __restrict__ Bt1, unsigned short* __restrict__ Bt2)
{
    __shared__ __align__(16) int sm[RNG];          // 25000B (count blocks only)
    const int tid = threadIdx.x;
    const int bid = blockIdx.x;

    if (bid >= NCNT) {                             // ---- prep body ----
        int t = (bid - NCNT) * 1024 + tid;
        if (t < 64 * 320) {
            int c = t / 320, k = t % 320;
            Bt1[t] = (k < 300) ? f2bf(W1[k * 64 + c]) : (unsigned short)0;
        } else {
            int i = t - 64 * 320;
            int c = i >> 6, k = i & 63;
            Bt2[i] = f2bf(W2[k * 64 + c]);
        }
        return;
    }
    // ---- count body: chunk c, range w ----
    const int c = bid >> 3, w = bid & 7;
    const int lo = w * RNG;
    for (int j = tid; j < RNG; j += 1024) sm[j] = 0;
    __syncthreads();
    const int base = c << CSH;
    #pragma unroll
    for (int it = 0; it < (1 << CSH) / 4096; ++it) {
        int e = base + (it * 1024 + tid) * 4;
        if (e < NE) {                               // NE%4==0 -> whole int4 valid
            int4 d = *(const int4*)(ei + NE + e);
            unsigned t0 = (unsigned)(d.x - lo), t1 = (unsigned)(d.y - lo);
            unsigned t2 = (unsigned)(d.z - lo), t3 = (unsigned)(d.w - lo);
            if (t0 < RNG) pos[e]     = (unsigned char)atomicAdd(&sm[t0], 1);
            if (t1 < RNG) pos[e + 1] = (unsigned char)atomicAdd(&sm[t1], 1);
            if (t2 < RNG) pos[e + 2] = (unsigned char)atomicAdd(&sm[t2], 1);
            if (t3 < RNG) pos[e + 3] = (unsigned char)atomicAdd(&sm[t3], 1);
        }
    }
    __syncthreads();
    int* dstp = cnt + (size_t)bid * RPAD;          // exclusive region
    for (int j = tid; j < RNG; j += 1024) dstp[j] = sm[j];
}

// ---- FUSED: L1 MFMA GEMM (blocks [0,NGB)) + scan1 (tail blocks).
//      GEMM re-tiled BK=64: 5 K-iters (was 10) -> half the barriers, 64B/thread
//      A-loads. LDS 18.4KB -> still 8 blocks/CU. Scan1 re-shaped to 256thr. ----
__global__ __launch_bounds__(256) void k_gemm_scan(
        const float* __restrict__ A, const unsigned short* __restrict__ Bt,
        unsigned short* __restrict__ hb,
        const float* __restrict__ asrc, const float* __restrict__ adst,
        float* __restrict__ ss, float* __restrict__ sd,
        const int* __restrict__ cnt, int* __restrict__ excl,
        int* __restrict__ sums, unsigned char* __restrict__ rpre)
{
    __shared__ __align__(16) unsigned short lds[9216];   // 18432B
    const int tid = threadIdx.x;
    const int bid = blockIdx.x;

    if (bid >= NGB) {
        // ---------------- scan1 body (256 elements/block) ----------------
        const int sb = bid - NGB;
        int i = sb * 256 + tid;
        int v = 0;
        if (i < NN) {
            int w8 = i / RNG;                    // counter range 0..7
            int j = i - w8 * RNG;
            int run = 0;
            unsigned pk[ECP / 4];
            #pragma unroll
            for (int q = 0; q < ECP / 4; ++q) pk[q] = 0;
            #pragma unroll
            for (int cc = 0; cc < EC; ++cc) {
                pk[cc >> 2] |= ((unsigned)run & 0xffu) << ((cc & 3) * 8);
                run += cnt[(size_t)(cc * 8 + w8) * RPAD + j];
            }
            v = run;
            *(uint4*)(rpre + (size_t)i * ECP)      = make_uint4(pk[0], pk[1], pk[2], pk[3]);
            *(uint4*)(rpre + (size_t)i * ECP + 16) = make_uint4(pk[4], pk[5], pk[6], pk[7]);
        }
        int* buf = (int*)lds;
        buf[tid] = v;
        __syncthreads();
        #pragma unroll
        for (int off = 1; off < 256; off <<= 1) {
            int t = (tid >= off) ? buf[tid - off] : 0;
            __syncthreads();
            buf[tid] += t;
            __syncthreads();
        }
        if (i < NN) excl[i] = buf[tid] - v;
        if (tid == 255) sums[sb] = buf[255];
        return;
    }

    // ---------------- gemm body (HEADS=8, A fp32, K=300, BK=64, KT=5) ----------------
    const int row0 = bid * 64;
    const int lane = tid & 63, w = tid >> 6;
    const int quad = lane >> 4, mm = lane & 15;
    const int sr = tid >> 2, q16 = (tid & 3) * 16;
    const int gsr = row0 + sr;
    const int K = 300, M = NN;

    f32x4 acc[4];
    #pragma unroll
    for (int i = 0; i < 4; ++i) acc[i] = (f32x4){0.f, 0.f, 0.f, 0.f};

    for (int kt = 0; kt < 5; ++kt) {
        const int k0 = kt * 64;
        int4 a0 = {0, 0, 0, 0}, a1 = {0, 0, 0, 0};
        if (gsr < M) {
            const float* ap = A + (size_t)gsr * K + k0 + q16;
            unsigned short* u0 = (unsigned short*)&a0;
            unsigned short* u1 = (unsigned short*)&a1;
            if (k0 + q16 + 15 < K) {
                float4 v0 = *(const float4*)ap;
                float4 v1 = *(const float4*)(ap + 4);
                float4 v2 = *(const float4*)(ap + 8);
                float4 v3 = *(const float4*)(ap + 12);
                u0[0]=f2bf(v0.x); u0[1]=f2bf(v0.y); u0[2]=f2bf(v0.z); u0[3]=f2bf(v0.w);
                u0[4]=f2bf(v1.x); u0[5]=f2bf(v1.y); u0[6]=f2bf(v1.z); u0[7]=f2bf(v1.w);
                u1[0]=f2bf(v2.x); u1[1]=f2bf(v2.y); u1[2]=f2bf(v2.z); u1[3]=f2bf(v2.w);
                u1[4]=f2bf(v3.x); u1[5]=f2bf(v3.y); u1[6]=f2bf(v3.z); u1[7]=f2bf(v3.w);
            } else {
                #pragma unroll
                for (int j = 0; j < 8; ++j)
                    u0[j] = (k0 + q16 + j < K) ? f2bf(ap[j]) : (unsigned short)0;
                #pragma unroll
                for (int j = 0; j < 8; ++j)
                    u1[j] = (k0 + q16 + 8 + j < K) ? f2bf(ap[8 + j]) : (unsigned short)0;
            }
        }
        *(int4*)(lds + sr * 72 + q16)     = a0;
        *(int4*)(lds + sr * 72 + q16 + 8) = a1;
        *(int4*)(lds + 4608 + sr * 72 + q16) =
            *(const int4*)(Bt + (size_t)sr * 320 + k0 + q16);
        *(int4*)(lds + 4608 + sr * 72 + q16 + 8) =
            *(const int4*)(Bt + (size_t)sr * 320 + k0 + q16 + 8);
        __syncthreads();
        bf16x8 af0 = *(const bf16x8*)(lds + (w * 16 + mm) * 72 + quad * 8);
        bf16x8 af1 = *(const bf16x8*)(lds + (w * 16 + mm) * 72 + 32 + quad * 8);
        #pragma unroll
        for (int nt = 0; nt < 4; ++nt) {
            bf16x8 b0 = *(const bf16x8*)(lds + 4608 + (nt * 16 + mm) * 72 + quad * 8);
            bf16x8 b1 = *(const bf16x8*)(lds + 4608 + (nt * 16 + mm) * 72 + 32 + quad * 8);
            acc[nt] = __builtin_amdgcn_mfma_f32_16x16x32_bf16(af0, b0, acc[nt], 0, 0, 0);
            acc[nt] = __builtin_amdgcn_mfma_f32_16x16x32_bf16(af1, b1, acc[nt], 0, 0, 0);
        }
        __syncthreads();
    }
    // epilogue: C (col=lane&15, row=quad*4+reg) -> LDS bf16 tile (stride 72)
    #pragma unroll
    for (int nt = 0; nt < 4; ++nt)
        #pragma unroll
        for (int reg = 0; reg < 4; ++reg)
            lds[w * 1152 + (quad * 4 + reg) * 72 + nt * 16 + mm] = f2bf(acc[nt][reg]);
    __syncthreads();
    const int cg = (tid & 3) * 16;
    const unsigned short* crow = lds + (sr >> 4) * 1152 + (sr & 15) * 72;
    if (gsr < M) {
        *(int4*)(hb + (size_t)gsr * 64 + cg)     = *(const int4*)(crow + cg);
        *(int4*)(hb + (size_t)gsr * 64 + cg + 8) = *(const int4*)(crow + cg + 8);
    }
    #pragma unroll
    for (int hh = 0; hh < 2; ++hh) {
        int hd = (tid & 3) + hh * 4;
        float pss = 0.f, psd = 0.f;
        #pragma unroll
        for (int c = 0; c < 8; ++c) {
            float hv = bf2f(crow[hd * 8 + c]);
            pss += hv * asrc[hd * 8 + c];
            psd += hv * adst[hd * 8 + c];
        }
        if (gsr < M) { ss[gsr * 8 + hd] = pss; sd[gsr * 8 + hd] = psd; }
    }
}

// ---- MFMA GEMM layer 2 (A bf16, K=64 single tile, 1 barrier pair) ----
__global__ __launch_bounds__(256) void gemm_l2(const unsigned short* __restrict__ A,
        const unsigned short* __restrict__ Bt, unsigned short* __restrict__ hb,
        const float* __restrict__ asrc, const float* __restrict__ adst,
        float* __restrict__ ss, float* __restrict__ sd)
{
    __shared__ __align__(16) unsigned short lds[9216];
    const int tid  = threadIdx.x;
    const int row0 = blockIdx.x * 64;
    const int lane = tid & 63, w = tid >> 6;
    const int quad = lane >> 4, mm = lane & 15;
    const int sr = tid >> 2, q16 = (tid & 3) * 16;
    const int gsr = row0 + sr;

    f32x4 acc[4];
    #pragma unroll
    for (int i = 0; i < 4; ++i) acc[i] = (f32x4){0.f, 0.f, 0.f, 0.f};

    int4 a0 = {0, 0, 0, 0}, a1 = {0, 0, 0, 0};
    if (gsr < NN) {
        a0 = *(const int4*)(A + (size_t)gsr * 64 + q16);
        a1 = *(const int4*)(A + (size_t)gsr * 64 + q16 + 8);
    }
    *(int4*)(lds + sr * 72 + q16)     = a0;
    *(int4*)(lds + sr * 72 + q16 + 8) = a1;
    *(int4*)(lds + 4608 + sr * 72 + q16)     = *(const int4*)(Bt + sr * 64 + q16);
    *(int4*)(lds + 4608 + sr * 72 + q16 + 8) = *(const int4*)(Bt + sr * 64 + q16 + 8);
    __syncthreads();
    bf16x8 af0 = *(const bf16x8*)(lds + (w * 16 + mm) * 72 + quad * 8);
    bf16x8 af1 = *(const bf16x8*)(lds + (w * 16 + mm) * 72 + 32 + quad * 8);
    #pragma unroll
    for (int nt = 0; nt < 4; ++nt) {
        bf16x8 b0 = *(const bf16x8*)(lds + 4608 + (nt * 16 + mm) * 72 + quad * 8);
        bf16x8 b1 = *(const bf16x8*)(lds + 4608 + (nt * 16 + mm) * 72 + 32 + quad * 8);
        acc[nt] = __builtin_amdgcn_mfma_f32_16x16x32_bf16(af0, b0, acc[nt], 0, 0, 0);
        acc[nt] = __builtin_amdgcn_mfma_f32_16x16x32_bf16(af1, b1, acc[nt], 0, 0, 0);
    }
    __syncthreads();
    #pragma unroll
    for (int nt = 0; nt < 4; ++nt)
        #pragma unroll
        for (int reg = 0; reg < 4; ++reg)
            lds[w * 1152 + (quad * 4 + reg) * 72 + nt * 16 + mm] = f2bf(acc[nt][reg]);
    __syncthreads();
    const int cg = (tid & 3) * 16;
    const unsigned short* crow = lds + (sr >> 4) * 1152 + (sr & 15) * 72;
    if (gsr < NN) {
        *(int4*)(hb + (size_t)gsr * 64 + cg)     = *(const int4*)(crow + cg);
        *(int4*)(hb + (size_t)gsr * 64 + cg + 8) = *(const int4*)(crow + cg + 8);
    }
    int p = tid & 3;
    float pss = 0.f, psd = 0.f;
    #pragma unroll
    for (int c = 0; c < 16; ++c) {
        float hv = bf2f(crow[p * 16 + c]);
        pss += hv * asrc[p * 16 + c];
        psd += hv * adst[p * 16 + c];
    }
    pss += __shfl_xor(pss, 1); psd += __shfl_xor(psd, 1);
    pss += __shfl_xor(pss, 2); psd += __shfl_xor(psd, 2);
    if (p == 0 && gsr < NN) { ss[gsr] = pss; sd[gsr] = psd; }
}

// ------------- scan stage 2+3: each block scans 196 sums redundantly -------------
__global__ __launch_bounds__(1024) void scan23(const int* __restrict__ excl,
        const int* __restrict__ sums, int* __restrict__ rowptr)
{
    int blk = (int)blockIdx.x * 4;                  // 1024-block spans 4 scan1 blocks
    int off = 0;
    for (int j = 0; j < blk; ++j) off += sums[j];   // uniform scalar loop
    // within this 1024-span, add sums of the 4 covered scan1 blocks progressively
    int sub = (threadIdx.x >> 8);                   // which 256-group
    for (int j = 0; j < sub; ++j) off += sums[blk + j];
    int i = (int)blockIdx.x * 1024 + threadIdx.x;
    if (i < NN) rowptr[i] = excl[i] + off;
    if (i == 0) rowptr[NN] = NE;
}

// ------ CSR scatter: slot = rowptr[d] + rpre[d][chunk(e)] + pos[e] ------
__global__ __launch_bounds__(256) void scatter_k(const int* __restrict__ ei,
        const int* __restrict__ rowptr, const unsigned char* __restrict__ pos,
        const unsigned char* __restrict__ rpre, unsigned short* __restrict__ col)
{
    int e = (blockIdx.x * 256 + threadIdx.x) * 4;   // NE % 4 == 0
    if (e >= NE) return;
    int c = e >> CSH;                               // chunk uniform over the int4
    int4 s = *(const int4*)(ei + e);
    int4 d = *(const int4*)(ei + NE + e);
    uchar4 p = *(const uchar4*)(pos + e);
    int r0 = rowptr[d.x] + (int)rpre[(d.x << 5) + c] + p.x;
    int r1 = rowptr[d.y] + (int)rpre[(d.y << 5) + c] + p.y;
    int r2 = rowptr[d.z] + (int)rpre[(d.z << 5) + c] + p.z;
    int r3 = rowptr[d.w] + (int)rpre[(d.w << 5) + c] + p.w;
    col[r0] = (unsigned short)s.x;
    col[r1] = (unsigned short)s.y;
    col[r2] = (unsigned short)s.z;
    col[r3] = (unsigned short)s.w;
}

#define LEAKY(s) ((s) > 0.f ? (s) : 0.2f * (s))

// ------- layer1 agg: wave/node, 32 edges in flight (4 slots x 8-deep batch) -------
__global__ __launch_bounds__(256) void agg_l1(const int* __restrict__ rowptr,
        const unsigned short* __restrict__ col, const unsigned short* __restrict__ hb,
        const float* __restrict__ ss, const float* __restrict__ sd,
        const float* __restrict__ b, unsigned short* __restrict__ out)
{
    int n = (blockIdx.x * 256 + threadIdx.x) >> 6;
    int lane = threadIdx.x & 63;
    if (n >= NN) return;
    const int es = lane >> 4;            // edge slot 0..3
    const int cg = (lane & 15) << 2;     // channel group base
    const int hd = cg >> 3;              // head
    float sdst = sd[n * 8 + hd];
    int r0 = rowptr[n], r1 = rowptr[n + 1];
    f32x4 acc = {0.f, 0.f, 0.f, 0.f};
    float dsum = 0.f;
    for (int i = r0; i < r1; i += 32) {
        int av[8]; bool vv[8];
        #pragma unroll
        for (int u = 0; u < 8; ++u) {
            int e = i + u * 4 + es;
            vv[u] = e < r1;
            av[u] = (int)col[vv[u] ? e : r0];
        }
        uint2 rr[8]; float sv[8];
        #pragma unroll
        for (int u = 0; u < 8; ++u) {
            rr[u] = *(const uint2*)(hb + av[u] * 64 + cg);
            sv[u] = ss[av[u] * 8 + hd];
        }
        #pragma unroll
        for (int u = 0; u < 8; ++u) {
            float wv = vv[u] ? __expf(LEAKY(sv[u] + sdst)) : 0.f;
            acc[0] += wv * bflo(rr[u].x);
            acc[1] += wv * bfhi(rr[u].x);
            acc[2] += wv * bflo(rr[u].y);
            acc[3] += wv * bfhi(rr[u].y);
            dsum += wv;
        }
    }
    #pragma unroll
    for (int m = 16; m <= 32; m <<= 1) {
        acc[0] += __shfl_xor(acc[0], m); acc[1] += __shfl_xor(acc[1], m);
        acc[2] += __shfl_xor(acc[2], m); acc[3] += __shfl_xor(acc[3], m);
        dsum += __shfl_xor(dsum, m);
    }
    if (es == 0) {
        float inv = 1.f / (dsum + 1e-16f);
        float v0 = acc[0] * inv + b[cg + 0]; v0 = v0 > 0.f ? v0 : __expf(v0) - 1.f;
        float v1 = acc[1] * inv + b[cg + 1]; v1 = v1 > 0.f ? v1 : __expf(v1) - 1.f;
        float v2 = acc[2] * inv + b[cg + 2]; v2 = v2 > 0.f ? v2 : __expf(v2) - 1.f;
        float v3 = acc[3] * inv + b[cg + 3]; v3 = v3 > 0.f ? v3 : __expf(v3) - 1.f;
        unsigned o01 = (unsigned)f2bf(v0) | ((unsigned)f2bf(v1) << 16);
        unsigned o23 = (unsigned)f2bf(v2) | ((unsigned)f2bf(v3) << 16);
        *(uint2*)(out + n * 64 + cg) = make_uint2(o01, o23);
    }
}

// ------- layer2 agg: wave/node, 32 edges in flight, fp32 out -------
__global__ __launch_bounds__(256) void agg_l2(const int* __restrict__ rowptr,
        const unsigned short* __restrict__ col, const unsigned short* __restrict__ hb,
        const float* __restrict__ ss, const float* __restrict__ sd,
        const float* __restrict__ b, float* __restrict__ out)
{
    int n = (blockIdx.x * 256 + threadIdx.x) >> 6;
    int lane = threadIdx.x & 63;
    if (n >= NN) return;
    const int es = lane >> 4;
    const int cg = (lane & 15) << 2;
    float sdst = sd[n];
    int r0 = rowptr[n], r1 = rowptr[n + 1];
    f32x4 acc = {0.f, 0.f, 0.f, 0.f};
    float dsum = 0.f;
    for (int i = r0; i < r1; i += 32) {
        int av[8]; bool vv[8];
        #pragma unroll
        for (int u = 0; u < 8; ++u) {
            int e = i + u * 4 + es;
            vv[u] = e < r1;
            av[u] = (int)col[vv[u] ? e : r0];
        }
        uint2 rr[8]; float sv[8];
        #pragma unroll
        for (int u = 0; u < 8; ++u) {
            rr[u] = *(const uint2*)(hb + av[u] * 64 + cg);
            sv[u] = ss[av[u]];
        }
        #pragma unroll
        for (int u = 0; u < 8; ++u) {
            float wv = vv[u] ? __expf(LEAKY(sv[u] + sdst)) : 0.f;
            acc[0] += wv * bflo(rr[u].x);
            acc[1] += wv * bfhi(rr[u].x);
            acc[2] += wv * bflo(rr[u].y);
            acc[3] += wv * bfhi(rr[u].y);
            dsum += wv;
        }
    }
    #pragma unroll
    for (int m = 16; m <= 32; m <<= 1) {
        acc[0] += __shfl_xor(acc[0], m); acc[1] += __shfl_xor(acc[1], m);
        acc[2] += __shfl_xor(acc[2], m); acc[3] += __shfl_xor(acc[3], m);
        dsum += __shfl_xor(dsum, m);
    }
    if (es == 0) {
        float inv = 1.f / (dsum + 1e-16f);
        float4 o;
        o.x = acc[0] * inv + b[cg + 0];
        o.y = acc[1] * inv + b[cg + 1];
        o.z = acc[2] * inv + b[cg + 2];
        o.w = acc[3] * inv + b[cg + 3];
        *(float4*)(out + n * 64 + cg) = o;
    }
}

extern "C" void kernel_launch(void* const* d_in, const int* in_sizes, int n_in,
                              void* d_out, int out_size, void* d_ws, size_t ws_size,
                              hipStream_t stream)
{
    const float* x      = (const float*)d_in[0];
    const int*   ei     = (const int*)d_in[1];
    const float* W1     = (const float*)d_in[2];
    const float* a_src1 = (const float*)d_in[3];
    const float* a_dst1 = (const float*)d_in[4];
    const float* b1     = (const float*)d_in[5];
    const float* W2     = (const float*)d_in[6];
    const float* a_src2 = (const float*)d_in[7];
    const float* a_dst2 = (const float*)d_in[8];
    const float* b2     = (const float*)d_in[9];
    float* out = (float*)d_out;

    // workspace (16B-aligned blocks first)
    char* wp = (char*)d_ws;
    unsigned short* hb  = (unsigned short*)wp;  wp += (size_t)NN * 64 * 2;  // h1 then h2 (bf16)
    unsigned short* P1b = (unsigned short*)wp;  wp += (size_t)NN * 64 * 2;  // h2in (bf16)
    unsigned short* Bt1 = (unsigned short*)wp;  wp += (size_t)64 * 320 * 2; // W1^T bf16 padded
    unsigned short* Bt2 = (unsigned short*)wp;  wp += (size_t)64 * 64 * 2;  // W2^T bf16
    float* ss1 = (float*)wp;  wp += (size_t)NN * 8 * 4;
    float* sd1 = (float*)wp;  wp += (size_t)NN * 8 * 4;
    int* cnt    = (int*)wp;  wp += (size_t)NCNT * RPAD * 4;  // per-(chunk,range) counts
    unsigned char* rpre = (unsigned char*)wp;  wp += (size_t)NN * ECP;  // byte chunk-prefixes
    int* excl   = (int*)wp;  wp += (size_t)NN * 4;
    int* sums   = (int*)wp;  wp += 256 * 4;
    int* rowptr = (int*)wp;  wp += (size_t)(NN + 4) * 4;
    unsigned short* col = (unsigned short*)wp;  wp += (size_t)(NE + 8) * 2;
    unsigned char*  pos = (unsigned char*)wp;   wp += (size_t)NE;
    float* ss2 = ss1;                    // alias (layer1 logits dead in layer2)
    float* sd2 = ss1 + NN;

    const int NB = (NN + 1023) / 1024;   // 49

    // 7 dispatches (was 9): prep fused into count; scan1 fused into gemm
    k_count_prep<<<NCNT + NPB, 1024, 0, stream>>>(ei, cnt, pos, W1, W2, Bt1, Bt2);
    k_gemm_scan<<<NGB + NSB, 256, 0, stream>>>(
        x, Bt1, hb, a_src1, a_dst1, ss1, sd1, cnt, excl, sums, rpre);
    scan23<<<NB, 1024, 0, stream>>>(excl, sums, rowptr);
    scatter_k<<<(NE / 4 + 255) / 256, 256, 0, stream>>>(ei, rowptr, pos, rpre, col);

    agg_l1<<<(NN * 64 + 255) / 256, 256, 0, stream>>>(rowptr, col, hb, ss1, sd1, b1, P1b);
    gemm_l2<<<(NN + 63) / 64, 256, 0, stream>>>(P1b, Bt2, hb, a_src2, a_dst2, ss2, sd2);
    agg_l2<<<(NN * 64 + 255) / 256, 256, 0, stream>>>(rowptr, col, hb, ss2, sd2, b2, out);
}